// Round 3
// baseline (458.353 us; speedup 1.0000x reference)
//
#include <hip/hip_runtime.h>

#define NN 100000
#define NE 600000
#define D  128
#define CHUNK 1024
#define NCH ((NN + CHUNK - 1) / CHUNK)   // 98
#define OH 64                            // outputs per block-half
#define NPW 16                           // nodes per wave-tile
#define NTILES (NN / NPW)                // 6250 (exact)

// ---------------- CSR build ----------------

__global__ void zero_kernel(int* __restrict__ p, int n) {
    int i = blockIdx.x * blockDim.x + threadIdx.x;
    if (i < n) p[i] = 0;
}

__global__ void hist_kernel(const int* __restrict__ dst, int* __restrict__ counts, int e) {
    int i = blockIdx.x * blockDim.x + threadIdx.x;
    if (i < e) atomicAdd(&counts[dst[i]], 1);
}

__global__ __launch_bounds__(256) void chunk_sum_kernel(const int* __restrict__ counts,
                                                        int* __restrict__ bsum, int n) {
    __shared__ int s[256];
    int c = blockIdx.x, t = threadIdx.x;
    int sum = 0;
    int end = (c + 1) * CHUNK; if (end > n) end = n;
    for (int i = c * CHUNK + t; i < end; i += 256) sum += counts[i];
    s[t] = sum; __syncthreads();
    for (int off = 128; off > 0; off >>= 1) {
        if (t < off) s[t] += s[t + off];
        __syncthreads();
    }
    if (t == 0) bsum[c] = s[0];
}

__global__ __launch_bounds__(128) void chunk_scan_kernel(const int* __restrict__ bsum,
                                                         int* __restrict__ bpre,
                                                         int* __restrict__ offsets) {
    __shared__ int s[128];
    int t = threadIdx.x;
    int v = (t < NCH) ? bsum[t] : 0;
    s[t] = v; __syncthreads();
    for (int off = 1; off < 128; off <<= 1) {
        int u = (t >= off) ? s[t - off] : 0;
        __syncthreads();
        s[t] += u;
        __syncthreads();
    }
    if (t < NCH) bpre[t] = s[t] - v;
    if (t == 127) offsets[NN] = s[127];
}

__global__ __launch_bounds__(CHUNK) void offsets_kernel(const int* __restrict__ counts,
                                                        const int* __restrict__ bpre,
                                                        int* __restrict__ offsets,
                                                        int* __restrict__ cursor, int n) {
    __shared__ int s[CHUNK];
    int t = threadIdx.x;
    int i = blockIdx.x * CHUNK + t;
    int v = (i < n) ? counts[i] : 0;
    s[t] = v; __syncthreads();
    for (int off = 1; off < CHUNK; off <<= 1) {
        int u = (t >= off) ? s[t - off] : 0;
        __syncthreads();
        s[t] += u;
        __syncthreads();
    }
    if (i < n) {
        int ex = s[t] - v + bpre[blockIdx.x];
        offsets[i] = ex;
        cursor[i]  = ex;
    }
}

__global__ void scatter_kernel(const int* __restrict__ src, const int* __restrict__ dst,
                               int* __restrict__ cursor, int* __restrict__ sorted_src, int e) {
    int i = blockIdx.x * blockDim.x + threadIdx.x;
    if (i < e) {
        int d = dst[i];
        int pos = atomicAdd(&cursor[d], 1);
        sorted_src[pos] = src[i];
    }
}

// ---------------- segment product ----------------
// float4 lanes: 32 lanes per row, 8 rows per 256-thread block, x2 edge unroll.
__global__ __launch_bounds__(256) void aggregate_kernel(const float* __restrict__ x,
                                                        const int* __restrict__ offsets,
                                                        const int* __restrict__ ssrc,
                                                        float* __restrict__ aggr, int n) {
    int q4 = (threadIdx.x & 31) << 2;   // float4 offset in row
    int slot = threadIdx.x >> 5;        // 0..7
    for (int node = blockIdx.x * 8 + slot; node < n; node += gridDim.x * 8) {
        int b = offsets[node], e2 = offsets[node + 1];
        float4 p0 = make_float4(1.f, 1.f, 1.f, 1.f);
        float4 p1 = make_float4(1.f, 1.f, 1.f, 1.f);
        int i = b;
        for (; i + 2 <= e2; i += 2) {
            int s0 = ssrc[i], s1 = ssrc[i + 1];
            float4 v0 = *(const float4*)&x[(size_t)s0 * D + q4];
            float4 v1 = *(const float4*)&x[(size_t)s1 * D + q4];
            p0.x *= v0.x; p0.y *= v0.y; p0.z *= v0.z; p0.w *= v0.w;
            p1.x *= v1.x; p1.y *= v1.y; p1.z *= v1.z; p1.w *= v1.w;
        }
        if (i < e2) {
            float4 v0 = *(const float4*)&x[(size_t)ssrc[i] * D + q4];
            p0.x *= v0.x; p0.y *= v0.y; p0.z *= v0.z; p0.w *= v0.w;
        }
        float4 r;
        r.x = p0.x * p1.x; r.y = p0.y * p1.y; r.z = p0.z * p1.z; r.w = p0.w * p1.w;
        *(float4*)&aggr[(size_t)node * D + q4] = r;
    }
}

// ---------------- fused dual-GEMM + multiply ----------------
// out[n][o] = (x[n].W1[o] + b1[o]) * (aggr[n].W2[o] + b2[o])
// O-split: half = blockIdx.x & 1 owns outputs [half*64, half*64+64).
// LDS = 2 * 64 * 129 * 4 = 66 KB  -> 2 blocks/CU -> 4 waves/SIMD.
// 512 threads = 8 waves; each wave owns 16 nodes; lane l owns output oBase+l.
// W rows at stride 129: conflict-free ds_read_b128. x/aggr reads are
// wave-uniform (broadcast) -> one 16B request per wave per load.
__global__ __launch_bounds__(512) void fused_kernel(const float* __restrict__ x,
                                                    const float* __restrict__ aggr,
                                                    const float* __restrict__ W1,
                                                    const float* __restrict__ b1,
                                                    const float* __restrict__ W2,
                                                    const float* __restrict__ b2,
                                                    float* __restrict__ out, int n) {
    __shared__ float sW1[OH * 129];
    __shared__ float sW2[OH * 129];

    const int half  = blockIdx.x & 1;
    const int oBase = half * OH;

    for (int i = threadIdx.x; i < OH * D; i += 512) {
        int r = i >> 7, k = i & (D - 1);    // coalesced global, conflict-free LDS write
        sW1[r * 129 + k] = W1[(oBase + r) * D + k];
        sW2[r * 129 + k] = W2[(oBase + r) * D + k];
    }
    const int lane = threadIdx.x & 63;
    const int wv = __builtin_amdgcn_readfirstlane((int)(threadIdx.x >> 6)); // 0..7
    const int o = oBase + lane;
    const float bb1 = b1[o], bb2 = b2[o];
    __syncthreads();

    const int tile = (blockIdx.x >> 1) * 8 + wv;    // wave-tile id
    if (tile >= NTILES) return;
    const int base = tile * NPW;

    const float* __restrict__ w1 = &sW1[lane * 129];
    const float* __restrict__ w2 = &sW2[lane * 129];
    const float* __restrict__ xp = &x[(size_t)base * D];
    const float* __restrict__ ap = &aggr[(size_t)base * D];

    float a1[NPW], a2[NPW];
#pragma unroll
    for (int j = 0; j < NPW; ++j) { a1[j] = 0.f; a2[j] = 0.f; }

#pragma unroll 2
    for (int kb = 0; kb < D; kb += 4) {
        const float4 u1 = *(const float4*)&w1[kb];
        const float4 u2 = *(const float4*)&w2[kb];
#pragma unroll
        for (int j = 0; j < NPW; ++j) {
            const float4 xv = *(const float4*)&xp[j * D + kb];   // wave-uniform
            const float4 av = *(const float4*)&ap[j * D + kb];
            a1[j] += xv.x * u1.x + xv.y * u1.y + xv.z * u1.z + xv.w * u1.w;
            a2[j] += av.x * u2.x + av.y * u2.y + av.z * u2.z + av.w * u2.w;
        }
    }
#pragma unroll
    for (int j = 0; j < NPW; ++j) {
        out[(size_t)(base + j) * D + o] = (a1[j] + bb1) * (a2[j] + bb2);
    }
}

// ---------------- launch ----------------

extern "C" void kernel_launch(void* const* d_in, const int* in_sizes, int n_in,
                              void* d_out, int out_size, void* d_ws, size_t ws_size,
                              hipStream_t stream) {
    const float* x  = (const float*)d_in[0];
    const int*   ei = (const int*)d_in[1];
    const float* W1 = (const float*)d_in[2];
    const float* b1 = (const float*)d_in[3];
    const float* W2 = (const float*)d_in[4];
    const float* b2 = (const float*)d_in[5];
    float* out = (float*)d_out;

    const int n = NN, e = NE;
    const int* src = ei;          // edge_index[0]
    const int* dst = ei + e;      // edge_index[1]

    char* ws = (char*)d_ws;
    float* aggr = (float*)ws;               ws += (size_t)n * D * sizeof(float);
    int* counts = (int*)ws;                 ws += (size_t)n * sizeof(int);
    int* offsets = (int*)ws;                ws += (size_t)(n + 1) * sizeof(int);
    ws += 256 - ((uintptr_t)ws & 255);
    int* cursor = (int*)ws;                 ws += (size_t)n * sizeof(int);
    int* sorted_src = (int*)ws;             ws += (size_t)e * sizeof(int);
    int* bsum = (int*)ws;                   ws += (size_t)NCH * sizeof(int);
    int* bpre = (int*)ws;                   /* NCH ints */

    zero_kernel<<<(n + 255) / 256, 256, 0, stream>>>(counts, n);
    hist_kernel<<<(e + 255) / 256, 256, 0, stream>>>(dst, counts, e);
    chunk_sum_kernel<<<NCH, 256, 0, stream>>>(counts, bsum, n);
    chunk_scan_kernel<<<1, 128, 0, stream>>>(bsum, bpre, offsets);
    offsets_kernel<<<NCH, CHUNK, 0, stream>>>(counts, bpre, offsets, cursor, n);
    scatter_kernel<<<(e + 255) / 256, 256, 0, stream>>>(src, dst, cursor, sorted_src, e);
    aggregate_kernel<<<2048, 256, 0, stream>>>(x, offsets, sorted_src, aggr, n);

    // grid: ceil(NTILES/8) tile-blocks x 2 O-halves, halves interleaved for L2 reuse
    int nblk = ((NTILES + 7) / 8) * 2;   // 782 * 2 = 1564
    fused_kernel<<<nblk, 512, 0, stream>>>(x, aggr, W1, b1, W2, b2, out, n);
}

// Round 4
// 374.144 us; speedup vs baseline: 1.2251x; 1.2251x over previous
//
#include <hip/hip_runtime.h>

#define NN 100000
#define NE 600000
#define D  128
#define CHUNK 1024
#define NCH ((NN + CHUNK - 1) / CHUNK)   // 98
#define NT (NN / 16)                     // 6250 node-tiles (exact)

typedef __attribute__((ext_vector_type(8))) short short8;
typedef __attribute__((ext_vector_type(4))) float floatx4;

__device__ __forceinline__ unsigned short f2bf(float f) {
    union { float f; unsigned int u; } a; a.f = f;
    unsigned int r = a.u + 0x7fff + ((a.u >> 16) & 1);   // RNE
    return (unsigned short)(r >> 16);
}
__device__ __forceinline__ float bf2f(unsigned short h) {
    union { unsigned int u; float f; } a; a.u = ((unsigned int)h) << 16;
    return a.f;
}

// ---------------- CSR build ----------------

__global__ void zero_kernel(int* __restrict__ p, int n) {
    int i = blockIdx.x * blockDim.x + threadIdx.x;
    if (i < n) p[i] = 0;
}

__global__ void hist_kernel(const int* __restrict__ dst, int* __restrict__ counts, int e) {
    int i = blockIdx.x * blockDim.x + threadIdx.x;
    if (i < e) atomicAdd(&counts[dst[i]], 1);
}

__global__ __launch_bounds__(256) void chunk_sum_kernel(const int* __restrict__ counts,
                                                        int* __restrict__ bsum, int n) {
    __shared__ int s[256];
    int c = blockIdx.x, t = threadIdx.x;
    int sum = 0;
    int end = (c + 1) * CHUNK; if (end > n) end = n;
    for (int i = c * CHUNK + t; i < end; i += 256) sum += counts[i];
    s[t] = sum; __syncthreads();
    for (int off = 128; off > 0; off >>= 1) {
        if (t < off) s[t] += s[t + off];
        __syncthreads();
    }
    if (t == 0) bsum[c] = s[0];
}

__global__ __launch_bounds__(128) void chunk_scan_kernel(const int* __restrict__ bsum,
                                                         int* __restrict__ bpre,
                                                         int* __restrict__ offsets) {
    __shared__ int s[128];
    int t = threadIdx.x;
    int v = (t < NCH) ? bsum[t] : 0;
    s[t] = v; __syncthreads();
    for (int off = 1; off < 128; off <<= 1) {
        int u = (t >= off) ? s[t - off] : 0;
        __syncthreads();
        s[t] += u;
        __syncthreads();
    }
    if (t < NCH) bpre[t] = s[t] - v;
    if (t == 127) offsets[NN] = s[127];
}

__global__ __launch_bounds__(CHUNK) void offsets_kernel(const int* __restrict__ counts,
                                                        const int* __restrict__ bpre,
                                                        int* __restrict__ offsets,
                                                        int* __restrict__ cursor, int n) {
    __shared__ int s[CHUNK];
    int t = threadIdx.x;
    int i = blockIdx.x * CHUNK + t;
    int v = (i < n) ? counts[i] : 0;
    s[t] = v; __syncthreads();
    for (int off = 1; off < CHUNK; off <<= 1) {
        int u = (t >= off) ? s[t - off] : 0;
        __syncthreads();
        s[t] += u;
        __syncthreads();
    }
    if (i < n) {
        int ex = s[t] - v + bpre[blockIdx.x];
        offsets[i] = ex;
        cursor[i]  = ex;
    }
}

__global__ void scatter_kernel(const int* __restrict__ src, const int* __restrict__ dst,
                               int* __restrict__ cursor, int* __restrict__ sorted_src, int e) {
    int i = blockIdx.x * blockDim.x + threadIdx.x;
    if (i < e) {
        int d = dst[i];
        int pos = atomicAdd(&cursor[d], 1);
        sorted_src[pos] = src[i];
    }
}

// ---------------- segment product (writes split-bf16 aggr) ----------------

__global__ __launch_bounds__(256) void aggregate_kernel(const float* __restrict__ x,
                                                        const int* __restrict__ offsets,
                                                        const int* __restrict__ ssrc,
                                                        unsigned short* __restrict__ ahi,
                                                        unsigned short* __restrict__ alo,
                                                        int n) {
    int q4 = (threadIdx.x & 31) << 2;   // float4 offset in row
    int slot = threadIdx.x >> 5;        // 0..7
    for (int node = blockIdx.x * 8 + slot; node < n; node += gridDim.x * 8) {
        int b = offsets[node], e2 = offsets[node + 1];
        float4 p0 = make_float4(1.f, 1.f, 1.f, 1.f);
        float4 p1 = make_float4(1.f, 1.f, 1.f, 1.f);
        int i = b;
        for (; i + 2 <= e2; i += 2) {
            int s0 = ssrc[i], s1 = ssrc[i + 1];
            float4 v0 = *(const float4*)&x[(size_t)s0 * D + q4];
            float4 v1 = *(const float4*)&x[(size_t)s1 * D + q4];
            p0.x *= v0.x; p0.y *= v0.y; p0.z *= v0.z; p0.w *= v0.w;
            p1.x *= v1.x; p1.y *= v1.y; p1.z *= v1.z; p1.w *= v1.w;
        }
        if (i < e2) {
            float4 v0 = *(const float4*)&x[(size_t)ssrc[i] * D + q4];
            p0.x *= v0.x; p0.y *= v0.y; p0.z *= v0.z; p0.w *= v0.w;
        }
        float r[4];
        r[0] = p0.x * p1.x; r[1] = p0.y * p1.y; r[2] = p0.z * p1.z; r[3] = p0.w * p1.w;
        ushort4 h, l;
        h.x = f2bf(r[0]); l.x = f2bf(r[0] - bf2f(h.x));
        h.y = f2bf(r[1]); l.y = f2bf(r[1] - bf2f(h.y));
        h.z = f2bf(r[2]); l.z = f2bf(r[2] - bf2f(h.z));
        h.w = f2bf(r[3]); l.w = f2bf(r[3] - bf2f(h.w));
        *(ushort4*)&ahi[(size_t)node * D + q4] = h;
        *(ushort4*)&alo[(size_t)node * D + q4] = l;
    }
}

// ---------------- W -> split-bf16 MFMA-fragment order ----------------
// wfrag[mat][c][q][lane], 16B per slot. mat: 0=W1hi 1=W1lo 2=W2hi 3=W2lo.
// B-frag for col-tile c, k-chunk q: lane l holds W[c*16 + (l&15)][q*32 + 8*(l>>4) + j].
__global__ void wprep_kernel(const float* __restrict__ W1, const float* __restrict__ W2,
                             short8* __restrict__ wfrag) {
    int idx = blockIdx.x * 256 + threadIdx.x;
    if (idx >= 4096) return;
    int m2 = idx >> 11;                 // 0: W1, 1: W2
    int rem = idx & 2047;
    int c = rem >> 8;
    int q = (rem >> 6) & 3;
    int l = rem & 63;
    const float* W = m2 ? W2 : W1;
    int row = c * 16 + (l & 15);
    int kb = q * 32 + 8 * (l >> 4);
    const float* src = &W[row * D + kb];
    short8 h, lo;
#pragma unroll
    for (int j = 0; j < 8; ++j) {
        float v = src[j];
        unsigned short hh = f2bf(v);
        h[j]  = (short)hh;
        lo[j] = (short)f2bf(v - bf2f(hh));
    }
    wfrag[(((m2 * 2 + 0) * 8 + c) * 4 + q) * 64 + l] = h;
    wfrag[(((m2 * 2 + 1) * 8 + c) * 4 + q) * 64 + l] = lo;
}

// ---------------- fused dual split-bf16 MFMA GEMM + multiply ----------------
// 512 thr = 8 waves, 1 block/CU (128 KB LDS). Wave owns a 16-node tile,
// computes all 128 outputs: C[m][n] = sum_k A[m][k] * W[n][k] via
// mfma_f32_16x16x32_bf16, 3-pass split per GEMM (hh + hl + lh).
// C/D: col = lane&15, row = (lane>>4)*4 + reg  [guide §3, m89-verified].
__global__ __launch_bounds__(512, 2) void fused_kernel(const float* __restrict__ x,
                                                       const unsigned short* __restrict__ ahi,
                                                       const unsigned short* __restrict__ alo,
                                                       const short8* __restrict__ wfrag,
                                                       const float* __restrict__ b1,
                                                       const float* __restrict__ b2,
                                                       float* __restrict__ out) {
    __shared__ short8 sW[4 * 8 * 4 * 64];          // 128 KB
    for (int i = threadIdx.x; i < 8192; i += 512) sW[i] = wfrag[i];

    const int lane = threadIdx.x & 63;
    const int wv   = threadIdx.x >> 6;             // 0..7
    const int r16  = lane & 15;
    const int g    = lane >> 4;                    // 0..3

    float bias1[8], bias2[8];
#pragma unroll
    for (int c = 0; c < 8; ++c) {
        bias1[c] = b1[c * 16 + r16];
        bias2[c] = b2[c * 16 + r16];
    }
    __syncthreads();

    for (int tile = blockIdx.x * 8 + wv; tile < NT; tile += gridDim.x * 8) {
        const int base = tile * 16;
        const float*          xrow = &x  [(size_t)(base + r16) * D + g * 8];
        const unsigned short* ahr  = &ahi[(size_t)(base + r16) * D + g * 8];
        const unsigned short* alr  = &alo[(size_t)(base + r16) * D + g * 8];

        short8 axh[4], axl[4], aah[4], aal[4];
#pragma unroll
        for (int q = 0; q < 4; ++q) {
            floatx4 v0 = *(const floatx4*)&xrow[q * 32];
            floatx4 v1 = *(const floatx4*)&xrow[q * 32 + 4];
            short8 h, l;
#pragma unroll
            for (int j = 0; j < 4; ++j) {
                unsigned short hh = f2bf(v0[j]);
                h[j] = (short)hh;
                l[j] = (short)f2bf(v0[j] - bf2f(hh));
                unsigned short hh2 = f2bf(v1[j]);
                h[4 + j] = (short)hh2;
                l[4 + j] = (short)f2bf(v1[j] - bf2f(hh2));
            }
            axh[q] = h; axl[q] = l;
            aah[q] = *(const short8*)&ahr[q * 32];
            aal[q] = *(const short8*)&alr[q * 32];
        }

        floatx4 c1[8], c2[8];
#pragma unroll
        for (int c = 0; c < 8; ++c) { c1[c] = (floatx4)0.f; c2[c] = (floatx4)0.f; }

#pragma unroll
        for (int q = 0; q < 4; ++q) {
#pragma unroll
            for (int c = 0; c < 8; ++c) {
                short8 b1h = sW[((0 * 8 + c) * 4 + q) * 64 + lane];
                short8 b1l = sW[((1 * 8 + c) * 4 + q) * 64 + lane];
                short8 b2h = sW[((2 * 8 + c) * 4 + q) * 64 + lane];
                short8 b2l = sW[((3 * 8 + c) * 4 + q) * 64 + lane];
                c1[c] = __builtin_amdgcn_mfma_f32_16x16x32_bf16(axh[q], b1h, c1[c], 0, 0, 0);
                c1[c] = __builtin_amdgcn_mfma_f32_16x16x32_bf16(axl[q], b1h, c1[c], 0, 0, 0);
                c1[c] = __builtin_amdgcn_mfma_f32_16x16x32_bf16(axh[q], b1l, c1[c], 0, 0, 0);
                c2[c] = __builtin_amdgcn_mfma_f32_16x16x32_bf16(aah[q], b2h, c2[c], 0, 0, 0);
                c2[c] = __builtin_amdgcn_mfma_f32_16x16x32_bf16(aal[q], b2h, c2[c], 0, 0, 0);
                c2[c] = __builtin_amdgcn_mfma_f32_16x16x32_bf16(aah[q], b2l, c2[c], 0, 0, 0);
            }
        }

#pragma unroll
        for (int c = 0; c < 8; ++c) {
#pragma unroll
            for (int r = 0; r < 4; ++r) {
                float h1 = c1[c][r] + bias1[c];
                float h2 = c2[c][r] + bias2[c];
                out[(size_t)(base + g * 4 + r) * D + c * 16 + r16] = h1 * h2;
            }
        }
    }
}

// ---------------- launch ----------------

extern "C" void kernel_launch(void* const* d_in, const int* in_sizes, int n_in,
                              void* d_out, int out_size, void* d_ws, size_t ws_size,
                              hipStream_t stream) {
    const float* x  = (const float*)d_in[0];
    const int*   ei = (const int*)d_in[1];
    const float* W1 = (const float*)d_in[2];
    const float* b1 = (const float*)d_in[3];
    const float* W2 = (const float*)d_in[4];
    const float* b2 = (const float*)d_in[5];
    float* out = (float*)d_out;

    const int n = NN, e = NE;
    const int* src = ei;          // edge_index[0]
    const int* dst = ei + e;      // edge_index[1]

    char* ws = (char*)d_ws;
    unsigned short* ahi = (unsigned short*)ws;  ws += (size_t)n * D * 2;   // 25.6 MB
    unsigned short* alo = (unsigned short*)ws;  ws += (size_t)n * D * 2;   // 25.6 MB
    short8* wfrag = (short8*)ws;                ws += 8192 * 16;           // 128 KB
    int* counts = (int*)ws;                     ws += (size_t)n * sizeof(int);
    int* offsets = (int*)ws;                    ws += (size_t)(n + 1) * sizeof(int);
    ws += 256 - ((uintptr_t)ws & 255);
    int* cursor = (int*)ws;                     ws += (size_t)n * sizeof(int);
    int* sorted_src = (int*)ws;                 ws += (size_t)e * sizeof(int);
    int* bsum = (int*)ws;                       ws += (size_t)NCH * sizeof(int);
    int* bpre = (int*)ws;                       /* NCH ints */

    zero_kernel<<<(n + 255) / 256, 256, 0, stream>>>(counts, n);
    hist_kernel<<<(e + 255) / 256, 256, 0, stream>>>(dst, counts, e);
    chunk_sum_kernel<<<NCH, 256, 0, stream>>>(counts, bsum, n);
    chunk_scan_kernel<<<1, 128, 0, stream>>>(bsum, bpre, offsets);
    offsets_kernel<<<NCH, CHUNK, 0, stream>>>(counts, bpre, offsets, cursor, n);
    scatter_kernel<<<(e + 255) / 256, 256, 0, stream>>>(src, dst, cursor, sorted_src, e);
    wprep_kernel<<<16, 256, 0, stream>>>(W1, W2, wfrag);
    aggregate_kernel<<<2048, 256, 0, stream>>>(x, offsets, sorted_src, ahi, alo, n);
    fused_kernel<<<256, 512, 0, stream>>>(x, ahi, alo, wfrag, b1, b2, out);
}

// Round 5
// 355.857 us; speedup vs baseline: 1.2880x; 1.0514x over previous
//
#include <hip/hip_runtime.h>

#define NN 100000
#define NE 600000
#define D  128
#define CHUNK 1024
#define NCH ((NN + CHUNK - 1) / CHUNK)   // 98
#define NT (NN / 16)                     // 6250 node-tiles (exact)

typedef __attribute__((ext_vector_type(8))) short short8;
typedef __attribute__((ext_vector_type(4))) float floatx4;

__device__ __forceinline__ unsigned short f2bf(float f) {
    union { float f; unsigned int u; } a; a.f = f;
    unsigned int r = a.u + 0x7fff + ((a.u >> 16) & 1);   // RNE
    return (unsigned short)(r >> 16);
}
__device__ __forceinline__ float bf2f(unsigned short h) {
    union { unsigned int u; float f; } a; a.u = ((unsigned int)h) << 16;
    return a.f;
}

// ---------------- CSR build ----------------

__global__ void zero_kernel(int* __restrict__ p, int n) {
    int i = blockIdx.x * blockDim.x + threadIdx.x;
    if (i < n) p[i] = 0;
}

__global__ void hist_kernel(const int* __restrict__ dst, int* __restrict__ counts, int e) {
    int i = blockIdx.x * blockDim.x + threadIdx.x;
    if (i < e) atomicAdd(&counts[dst[i]], 1);
}

__global__ __launch_bounds__(256) void chunk_sum_kernel(const int* __restrict__ counts,
                                                        int* __restrict__ bsum, int n) {
    __shared__ int s[256];
    int c = blockIdx.x, t = threadIdx.x;
    int sum = 0;
    int end = (c + 1) * CHUNK; if (end > n) end = n;
    for (int i = c * CHUNK + t; i < end; i += 256) sum += counts[i];
    s[t] = sum; __syncthreads();
    for (int off = 128; off > 0; off >>= 1) {
        if (t < off) s[t] += s[t + off];
        __syncthreads();
    }
    if (t == 0) bsum[c] = s[0];
}

__global__ __launch_bounds__(128) void chunk_scan_kernel(const int* __restrict__ bsum,
                                                         int* __restrict__ bpre,
                                                         int* __restrict__ offsets) {
    __shared__ int s[128];
    int t = threadIdx.x;
    int v = (t < NCH) ? bsum[t] : 0;
    s[t] = v; __syncthreads();
    for (int off = 1; off < 128; off <<= 1) {
        int u = (t >= off) ? s[t - off] : 0;
        __syncthreads();
        s[t] += u;
        __syncthreads();
    }
    if (t < NCH) bpre[t] = s[t] - v;
    if (t == 127) offsets[NN] = s[127];
}

__global__ __launch_bounds__(CHUNK) void offsets_kernel(const int* __restrict__ counts,
                                                        const int* __restrict__ bpre,
                                                        int* __restrict__ offsets,
                                                        int* __restrict__ cursor, int n) {
    __shared__ int s[CHUNK];
    int t = threadIdx.x;
    int i = blockIdx.x * CHUNK + t;
    int v = (i < n) ? counts[i] : 0;
    s[t] = v; __syncthreads();
    for (int off = 1; off < CHUNK; off <<= 1) {
        int u = (t >= off) ? s[t - off] : 0;
        __syncthreads();
        s[t] += u;
        __syncthreads();
    }
    if (i < n) {
        int ex = s[t] - v + bpre[blockIdx.x];
        offsets[i] = ex;
        cursor[i]  = ex;
    }
}

__global__ void scatter_kernel(const int* __restrict__ src, const int* __restrict__ dst,
                               int* __restrict__ cursor, int* __restrict__ sorted_src, int e) {
    int i = blockIdx.x * blockDim.x + threadIdx.x;
    if (i < e) {
        int d = dst[i];
        int pos = atomicAdd(&cursor[d], 1);
        sorted_src[pos] = src[i];
    }
}

// ---------------- segment product (writes split-bf16 aggr) ----------------

__global__ __launch_bounds__(256) void aggregate_kernel(const float* __restrict__ x,
                                                        const int* __restrict__ offsets,
                                                        const int* __restrict__ ssrc,
                                                        unsigned short* __restrict__ ahi,
                                                        unsigned short* __restrict__ alo,
                                                        int n) {
    int q4 = (threadIdx.x & 31) << 2;   // float4 offset in row
    int slot = threadIdx.x >> 5;        // 0..7
    for (int node = blockIdx.x * 8 + slot; node < n; node += gridDim.x * 8) {
        int b = offsets[node], e2 = offsets[node + 1];
        float4 p0 = make_float4(1.f, 1.f, 1.f, 1.f);
        float4 p1 = make_float4(1.f, 1.f, 1.f, 1.f);
        int i = b;
        for (; i + 2 <= e2; i += 2) {
            int s0 = ssrc[i], s1 = ssrc[i + 1];
            float4 v0 = *(const float4*)&x[(size_t)s0 * D + q4];
            float4 v1 = *(const float4*)&x[(size_t)s1 * D + q4];
            p0.x *= v0.x; p0.y *= v0.y; p0.z *= v0.z; p0.w *= v0.w;
            p1.x *= v1.x; p1.y *= v1.y; p1.z *= v1.z; p1.w *= v1.w;
        }
        if (i < e2) {
            float4 v0 = *(const float4*)&x[(size_t)ssrc[i] * D + q4];
            p0.x *= v0.x; p0.y *= v0.y; p0.z *= v0.z; p0.w *= v0.w;
        }
        float r[4];
        r[0] = p0.x * p1.x; r[1] = p0.y * p1.y; r[2] = p0.z * p1.z; r[3] = p0.w * p1.w;
        ushort4 h, l;
        h.x = f2bf(r[0]); l.x = f2bf(r[0] - bf2f(h.x));
        h.y = f2bf(r[1]); l.y = f2bf(r[1] - bf2f(h.y));
        h.z = f2bf(r[2]); l.z = f2bf(r[2] - bf2f(h.z));
        h.w = f2bf(r[3]); l.w = f2bf(r[3] - bf2f(h.w));
        *(ushort4*)&ahi[(size_t)node * D + q4] = h;
        *(ushort4*)&alo[(size_t)node * D + q4] = l;
    }
}

// ---------------- W -> split-bf16 MFMA-fragment order ----------------
// wfrag[mat][c][q][lane], 16B per slot. mat: 0=W1hi 1=W1lo 2=W2hi 3=W2lo.
// B-frag for col-tile c, k-chunk q: lane l holds W[c*16 + (l&15)][q*32 + 8*(l>>4) + j].
__global__ void wprep_kernel(const float* __restrict__ W1, const float* __restrict__ W2,
                             short8* __restrict__ wfrag) {
    int idx = blockIdx.x * 256 + threadIdx.x;
    if (idx >= 4096) return;
    int m2 = idx >> 11;                 // 0: W1, 1: W2
    int rem = idx & 2047;
    int c = rem >> 8;
    int q = (rem >> 6) & 3;
    int l = rem & 63;
    const float* W = m2 ? W2 : W1;
    int row = c * 16 + (l & 15);
    int kb = q * 32 + 8 * (l >> 4);
    const float* src = &W[row * D + kb];
    short8 h, lo;
#pragma unroll
    for (int j = 0; j < 8; ++j) {
        float v = src[j];
        unsigned short hh = f2bf(v);
        h[j]  = (short)hh;
        lo[j] = (short)f2bf(v - bf2f(hh));
    }
    wfrag[(((m2 * 2 + 0) * 8 + c) * 4 + q) * 64 + l] = h;
    wfrag[(((m2 * 2 + 1) * 8 + c) * 4 + q) * 64 + l] = lo;
}

// ---------------- fused dual split-bf16 MFMA GEMM + multiply ----------------
// 512 thr = 8 waves, 1 block/CU (128 KB LDS) -> 2 waves/SIMD; VGPR<=256 is free.
// SEQUENTIAL GEMMs to keep ~120 live regs (round-4 version spilled: 376 MB FETCH).
// Wave owns a 16-node tile, all 128 outputs, 3-pass split bf16 (hh+lh+hl).
// C/D: col = lane&15, row = (lane>>4)*4 + reg.
__global__ __launch_bounds__(512) __attribute__((amdgpu_waves_per_eu(2)))
void fused_kernel(const float* __restrict__ x,
                  const unsigned short* __restrict__ ahi,
                  const unsigned short* __restrict__ alo,
                  const short8* __restrict__ wfrag,
                  const float* __restrict__ b1,
                  const float* __restrict__ b2,
                  float* __restrict__ out) {
    __shared__ short8 sW[4 * 8 * 4 * 64];          // 128 KB
    for (int i = threadIdx.x; i < 8192; i += 512) sW[i] = wfrag[i];

    const int lane = threadIdx.x & 63;
    const int wv   = threadIdx.x >> 6;             // 0..7
    const int r16  = lane & 15;
    const int g    = lane >> 4;                    // 0..3

    float bias1[8], bias2[8];
#pragma unroll
    for (int c = 0; c < 8; ++c) {
        bias1[c] = b1[c * 16 + r16];
        bias2[c] = b2[c * 16 + r16];
    }
    __syncthreads();

    for (int tile = blockIdx.x * 8 + wv; tile < NT; tile += gridDim.x * 8) {
        const int base = tile * 16;
        const size_t rowoff = (size_t)(base + r16) * D + g * 8;

        short8 fh[4], fl[4];
        // ---- phase 1: load+convert x fragments ----
        {
            const float* xr = &x[rowoff];
#pragma unroll
            for (int q = 0; q < 4; ++q) {
                floatx4 v0 = *(const floatx4*)&xr[q * 32];
                floatx4 v1 = *(const floatx4*)&xr[q * 32 + 4];
                short8 h, l;
#pragma unroll
                for (int j = 0; j < 4; ++j) {
                    unsigned short hh = f2bf(v0[j]);
                    h[j] = (short)hh;
                    l[j] = (short)f2bf(v0[j] - bf2f(hh));
                    unsigned short hh2 = f2bf(v1[j]);
                    h[4 + j] = (short)hh2;
                    l[4 + j] = (short)f2bf(v1[j] - bf2f(hh2));
                }
                fh[q] = h; fl[q] = l;
            }
        }
        floatx4 acc[8];
#pragma unroll
        for (int c = 0; c < 8; ++c) acc[c] = (floatx4)0.f;
#pragma unroll
        for (int q = 0; q < 4; ++q) {
#pragma unroll
            for (int c = 0; c < 8; ++c) {
                short8 bh = sW[((0 * 8 + c) * 4 + q) * 64 + lane];
                short8 bl = sW[((1 * 8 + c) * 4 + q) * 64 + lane];
                acc[c] = __builtin_amdgcn_mfma_f32_16x16x32_bf16(fh[q], bh, acc[c], 0, 0, 0);
                acc[c] = __builtin_amdgcn_mfma_f32_16x16x32_bf16(fl[q], bh, acc[c], 0, 0, 0);
                acc[c] = __builtin_amdgcn_mfma_f32_16x16x32_bf16(fh[q], bl, acc[c], 0, 0, 0);
            }
        }
        floatx4 h1[8];
#pragma unroll
        for (int c = 0; c < 8; ++c) {
            floatx4 t = acc[c];
            t[0] += bias1[c]; t[1] += bias1[c]; t[2] += bias1[c]; t[3] += bias1[c];
            h1[c] = t;
            acc[c] = (floatx4)0.f;
        }
        // ---- phase 2: aggr fragments (already split bf16) ----
        {
            const unsigned short* ahr = &ahi[rowoff];
            const unsigned short* alr = &alo[rowoff];
#pragma unroll
            for (int q = 0; q < 4; ++q) {
                fh[q] = *(const short8*)&ahr[q * 32];
                fl[q] = *(const short8*)&alr[q * 32];
            }
        }
#pragma unroll
        for (int q = 0; q < 4; ++q) {
#pragma unroll
            for (int c = 0; c < 8; ++c) {
                short8 bh = sW[((2 * 8 + c) * 4 + q) * 64 + lane];
                short8 bl = sW[((3 * 8 + c) * 4 + q) * 64 + lane];
                acc[c] = __builtin_amdgcn_mfma_f32_16x16x32_bf16(fh[q], bh, acc[c], 0, 0, 0);
                acc[c] = __builtin_amdgcn_mfma_f32_16x16x32_bf16(fl[q], bh, acc[c], 0, 0, 0);
                acc[c] = __builtin_amdgcn_mfma_f32_16x16x32_bf16(fh[q], bl, acc[c], 0, 0, 0);
            }
        }
        // ---- epilogue ----
#pragma unroll
        for (int c = 0; c < 8; ++c) {
#pragma unroll
            for (int r = 0; r < 4; ++r) {
                out[(size_t)(base + g * 4 + r) * D + c * 16 + r16] =
                    h1[c][r] * (acc[c][r] + bias2[c]);
            }
        }
    }
}

// ---------------- launch ----------------

extern "C" void kernel_launch(void* const* d_in, const int* in_sizes, int n_in,
                              void* d_out, int out_size, void* d_ws, size_t ws_size,
                              hipStream_t stream) {
    const float* x  = (const float*)d_in[0];
    const int*   ei = (const int*)d_in[1];
    const float* W1 = (const float*)d_in[2];
    const float* b1 = (const float*)d_in[3];
    const float* W2 = (const float*)d_in[4];
    const float* b2 = (const float*)d_in[5];
    float* out = (float*)d_out;

    const int n = NN, e = NE;
    const int* src = ei;          // edge_index[0]
    const int* dst = ei + e;      // edge_index[1]

    char* ws = (char*)d_ws;
    unsigned short* ahi = (unsigned short*)ws;  ws += (size_t)n * D * 2;   // 25.6 MB
    unsigned short* alo = (unsigned short*)ws;  ws += (size_t)n * D * 2;   // 25.6 MB
    short8* wfrag = (short8*)ws;                ws += 8192 * 16;           // 128 KB
    int* counts = (int*)ws;                     ws += (size_t)n * sizeof(int);
    int* offsets = (int*)ws;                    ws += (size_t)(n + 1) * sizeof(int);
    ws += 256 - ((uintptr_t)ws & 255);
    int* cursor = (int*)ws;                     ws += (size_t)n * sizeof(int);
    int* sorted_src = (int*)ws;                 ws += (size_t)e * sizeof(int);
    int* bsum = (int*)ws;                       ws += (size_t)NCH * sizeof(int);
    int* bpre = (int*)ws;                       /* NCH ints */

    zero_kernel<<<(n + 255) / 256, 256, 0, stream>>>(counts, n);
    hist_kernel<<<(e + 255) / 256, 256, 0, stream>>>(dst, counts, e);
    chunk_sum_kernel<<<NCH, 256, 0, stream>>>(counts, bsum, n);
    chunk_scan_kernel<<<1, 128, 0, stream>>>(bsum, bpre, offsets);
    offsets_kernel<<<NCH, CHUNK, 0, stream>>>(counts, bpre, offsets, cursor, n);
    scatter_kernel<<<(e + 255) / 256, 256, 0, stream>>>(src, dst, cursor, sorted_src, e);
    wprep_kernel<<<16, 256, 0, stream>>>(W1, W2, wfrag);
    aggregate_kernel<<<2048, 256, 0, stream>>>(x, offsets, sorted_src, ahi, alo, n);
    fused_kernel<<<256, 512, 0, stream>>>(x, ahi, alo, wfrag, b1, b2, out);
}

// Round 6
// 205.592 us; speedup vs baseline: 2.2294x; 1.7309x over previous
//
#include <hip/hip_runtime.h>

#define NN 100000
#define NE 600000
#define D  128
#define CHUNK 1024
#define NCH ((NN + CHUNK - 1) / CHUNK)   // 98
#define NT (NN / 16)                     // 6250 node-tiles (exact)

typedef __attribute__((ext_vector_type(8))) short short8;
typedef __attribute__((ext_vector_type(4))) float floatx4;

__device__ __forceinline__ unsigned short f2bf(float f) {
    union { float f; unsigned int u; } a; a.f = f;
    unsigned int r = a.u + 0x7fff + ((a.u >> 16) & 1);   // RNE
    return (unsigned short)(r >> 16);
}
__device__ __forceinline__ float bf2f(unsigned short h) {
    union { unsigned int u; float f; } a; a.u = ((unsigned int)h) << 16;
    return a.f;
}

// ---------------- CSR build ----------------

__global__ void zero_kernel(int* __restrict__ p, int n) {
    int i = blockIdx.x * blockDim.x + threadIdx.x;
    if (i < n) p[i] = 0;
}

__global__ void hist_kernel(const int* __restrict__ dst, int* __restrict__ counts, int e) {
    int i = blockIdx.x * blockDim.x + threadIdx.x;
    if (i < e) atomicAdd(&counts[dst[i]], 1);
}

__global__ __launch_bounds__(256) void chunk_sum_kernel(const int* __restrict__ counts,
                                                        int* __restrict__ bsum, int n) {
    __shared__ int s[256];
    int c = blockIdx.x, t = threadIdx.x;
    int sum = 0;
    int end = (c + 1) * CHUNK; if (end > n) end = n;
    for (int i = c * CHUNK + t; i < end; i += 256) sum += counts[i];
    s[t] = sum; __syncthreads();
    for (int off = 128; off > 0; off >>= 1) {
        if (t < off) s[t] += s[t + off];
        __syncthreads();
    }
    if (t == 0) bsum[c] = s[0];
}

__global__ __launch_bounds__(128) void chunk_scan_kernel(const int* __restrict__ bsum,
                                                         int* __restrict__ bpre,
                                                         int* __restrict__ offsets) {
    __shared__ int s[128];
    int t = threadIdx.x;
    int v = (t < NCH) ? bsum[t] : 0;
    s[t] = v; __syncthreads();
    for (int off = 1; off < 128; off <<= 1) {
        int u = (t >= off) ? s[t - off] : 0;
        __syncthreads();
        s[t] += u;
        __syncthreads();
    }
    if (t < NCH) bpre[t] = s[t] - v;
    if (t == 127) offsets[NN] = s[127];
}

__global__ __launch_bounds__(CHUNK) void offsets_kernel(const int* __restrict__ counts,
                                                        const int* __restrict__ bpre,
                                                        int* __restrict__ offsets,
                                                        int* __restrict__ cursor, int n) {
    __shared__ int s[CHUNK];
    int t = threadIdx.x;
    int i = blockIdx.x * CHUNK + t;
    int v = (i < n) ? counts[i] : 0;
    s[t] = v; __syncthreads();
    for (int off = 1; off < CHUNK; off <<= 1) {
        int u = (t >= off) ? s[t - off] : 0;
        __syncthreads();
        s[t] += u;
        __syncthreads();
    }
    if (i < n) {
        int ex = s[t] - v + bpre[blockIdx.x];
        offsets[i] = ex;
        cursor[i]  = ex;
    }
}

__global__ void scatter_kernel(const int* __restrict__ src, const int* __restrict__ dst,
                               int* __restrict__ cursor, int* __restrict__ sorted_src, int e) {
    int i = blockIdx.x * blockDim.x + threadIdx.x;
    if (i < e) {
        int d = dst[i];
        int pos = atomicAdd(&cursor[d], 1);
        sorted_src[pos] = src[i];
    }
}

// ---------------- segment product (writes split-bf16 aggr) ----------------

__global__ __launch_bounds__(256) void aggregate_kernel(const float* __restrict__ x,
                                                        const int* __restrict__ offsets,
                                                        const int* __restrict__ ssrc,
                                                        unsigned short* __restrict__ ahi,
                                                        unsigned short* __restrict__ alo,
                                                        int n) {
    int q4 = (threadIdx.x & 31) << 2;   // float4 offset in row
    int slot = threadIdx.x >> 5;        // 0..7
    for (int node = blockIdx.x * 8 + slot; node < n; node += gridDim.x * 8) {
        int b = offsets[node], e2 = offsets[node + 1];
        float4 p0 = make_float4(1.f, 1.f, 1.f, 1.f);
        float4 p1 = make_float4(1.f, 1.f, 1.f, 1.f);
        int i = b;
        for (; i + 2 <= e2; i += 2) {
            int s0 = ssrc[i], s1 = ssrc[i + 1];
            float4 v0 = *(const float4*)&x[(size_t)s0 * D + q4];
            float4 v1 = *(const float4*)&x[(size_t)s1 * D + q4];
            p0.x *= v0.x; p0.y *= v0.y; p0.z *= v0.z; p0.w *= v0.w;
            p1.x *= v1.x; p1.y *= v1.y; p1.z *= v1.z; p1.w *= v1.w;
        }
        if (i < e2) {
            float4 v0 = *(const float4*)&x[(size_t)ssrc[i] * D + q4];
            p0.x *= v0.x; p0.y *= v0.y; p0.z *= v0.z; p0.w *= v0.w;
        }
        float r[4];
        r[0] = p0.x * p1.x; r[1] = p0.y * p1.y; r[2] = p0.z * p1.z; r[3] = p0.w * p1.w;
        ushort4 h, l;
        h.x = f2bf(r[0]); l.x = f2bf(r[0] - bf2f(h.x));
        h.y = f2bf(r[1]); l.y = f2bf(r[1] - bf2f(h.y));
        h.z = f2bf(r[2]); l.z = f2bf(r[2] - bf2f(h.z));
        h.w = f2bf(r[3]); l.w = f2bf(r[3] - bf2f(h.w));
        *(ushort4*)&ahi[(size_t)node * D + q4] = h;
        *(ushort4*)&alo[(size_t)node * D + q4] = l;
    }
}

// ---------------- W -> split-bf16 MFMA-fragment order ----------------
// wfrag[mat][c][q][lane], 16B per slot. mat: 0=W1hi 1=W1lo 2=W2hi 3=W2lo.
// B-frag for col-tile c, k-chunk q: lane l holds W[c*16 + (l&15)][q*32 + 8*(l>>4) + j].
__global__ void wprep_kernel(const float* __restrict__ W1, const float* __restrict__ W2,
                             short8* __restrict__ wfrag) {
    int idx = blockIdx.x * 256 + threadIdx.x;
    if (idx >= 4096) return;
    int m2 = idx >> 11;                 // 0: W1, 1: W2
    int rem = idx & 2047;
    int c = rem >> 8;
    int q = (rem >> 6) & 3;
    int l = rem & 63;
    const float* W = m2 ? W2 : W1;
    int row = c * 16 + (l & 15);
    int kb = q * 32 + 8 * (l >> 4);
    const float* src = &W[row * D + kb];
    short8 h, lo;
#pragma unroll
    for (int j = 0; j < 8; ++j) {
        float v = src[j];
        unsigned short hh = f2bf(v);
        h[j]  = (short)hh;
        lo[j] = (short)f2bf(v - bf2f(hh));
    }
    wfrag[(((m2 * 2 + 0) * 8 + c) * 4 + q) * 64 + l] = h;
    wfrag[(((m2 * 2 + 1) * 8 + c) * 4 + q) * 64 + l] = lo;
}

// ---------------- fused dual split-bf16 MFMA GEMM + multiply ----------------
// 512 thr = 8 waves, 1 block/CU (128 KB LDS) -> 2 waves/SIMD.
// ROUND-6: spill fix. Wave owns 16 nodes x 64 OUTPUTS (4 col-tiles); waves pair
// per node-tile (wv&1 = column half). A-frags converted PER-q inside the loop
// (8 regs live, not 32). acc=16 + h1=16 + frag 8 + stage ~16 + bias 8 ~= 100 regs.
// __launch_bounds__(512,1): no artificial 128-VGPR cap (LDS already limits waves).
// C/D: col = lane&15, row = (lane>>4)*4 + reg.
__global__ __launch_bounds__(512, 1)
void fused_kernel(const float* __restrict__ x,
                  const unsigned short* __restrict__ ahi,
                  const unsigned short* __restrict__ alo,
                  const short8* __restrict__ wfrag,
                  const float* __restrict__ b1,
                  const float* __restrict__ b2,
                  float* __restrict__ out) {
    __shared__ short8 sW[4 * 8 * 4 * 64];          // 128 KB
    for (int i = threadIdx.x; i < 8192; i += 512) sW[i] = wfrag[i];

    const int lane  = threadIdx.x & 63;
    const int wv    = threadIdx.x >> 6;            // 0..7
    const int chalf = wv & 1;                      // column half: c = chalf*4 + cc
    const int r16   = lane & 15;
    const int g     = lane >> 4;                   // 0..3

    float bias1[4], bias2[4];
#pragma unroll
    for (int cc = 0; cc < 4; ++cc) {
        bias1[cc] = b1[(chalf * 4 + cc) * 16 + r16];
        bias2[cc] = b2[(chalf * 4 + cc) * 16 + r16];
    }
    __syncthreads();

    for (int tile = blockIdx.x * 4 + (wv >> 1); tile < NT; tile += gridDim.x * 4) {
        const int base = tile * 16;
        const size_t rowoff = (size_t)(base + r16) * D + g * 8;

        floatx4 acc[4];
#pragma unroll
        for (int cc = 0; cc < 4; ++cc) acc[cc] = (floatx4)0.f;

        // ---- phase 1: h1 = x . W1^T ----
        {
            const float* xr = &x[rowoff];
#pragma unroll
            for (int q = 0; q < 4; ++q) {
                floatx4 v0 = *(const floatx4*)&xr[q * 32];
                floatx4 v1 = *(const floatx4*)&xr[q * 32 + 4];
                short8 fh, fl;
#pragma unroll
                for (int j = 0; j < 4; ++j) {
                    unsigned short hh = f2bf(v0[j]);
                    fh[j] = (short)hh;
                    fl[j] = (short)f2bf(v0[j] - bf2f(hh));
                    unsigned short hh2 = f2bf(v1[j]);
                    fh[4 + j] = (short)hh2;
                    fl[4 + j] = (short)f2bf(v1[j] - bf2f(hh2));
                }
#pragma unroll
                for (int cc = 0; cc < 4; ++cc) {
                    const int c = chalf * 4 + cc;
                    short8 bh = sW[((0 * 8 + c) * 4 + q) * 64 + lane];
                    short8 bl = sW[((1 * 8 + c) * 4 + q) * 64 + lane];
                    acc[cc] = __builtin_amdgcn_mfma_f32_16x16x32_bf16(fh, bh, acc[cc], 0, 0, 0);
                    acc[cc] = __builtin_amdgcn_mfma_f32_16x16x32_bf16(fl, bh, acc[cc], 0, 0, 0);
                    acc[cc] = __builtin_amdgcn_mfma_f32_16x16x32_bf16(fh, bl, acc[cc], 0, 0, 0);
                }
            }
        }
        floatx4 h1[4];
#pragma unroll
        for (int cc = 0; cc < 4; ++cc) {
            floatx4 t = acc[cc];
            t[0] += bias1[cc]; t[1] += bias1[cc]; t[2] += bias1[cc]; t[3] += bias1[cc];
            h1[cc] = t;
            acc[cc] = (floatx4)0.f;
        }
        // ---- phase 2: h2 = aggr . W2^T (aggr already split-bf16) ----
        {
            const unsigned short* ahr = &ahi[rowoff];
            const unsigned short* alr = &alo[rowoff];
#pragma unroll
            for (int q = 0; q < 4; ++q) {
                short8 fh = *(const short8*)&ahr[q * 32];
                short8 fl = *(const short8*)&alr[q * 32];
#pragma unroll
                for (int cc = 0; cc < 4; ++cc) {
                    const int c = chalf * 4 + cc;
                    short8 bh = sW[((2 * 8 + c) * 4 + q) * 64 + lane];
                    short8 bl = sW[((3 * 8 + c) * 4 + q) * 64 + lane];
                    acc[cc] = __builtin_amdgcn_mfma_f32_16x16x32_bf16(fh, bh, acc[cc], 0, 0, 0);
                    acc[cc] = __builtin_amdgcn_mfma_f32_16x16x32_bf16(fl, bh, acc[cc], 0, 0, 0);
                    acc[cc] = __builtin_amdgcn_mfma_f32_16x16x32_bf16(fh, bl, acc[cc], 0, 0, 0);
                }
            }
        }
        // ---- epilogue ----
#pragma unroll
        for (int cc = 0; cc < 4; ++cc) {
            const int c = chalf * 4 + cc;
#pragma unroll
            for (int r = 0; r < 4; ++r) {
                out[(size_t)(base + g * 4 + r) * D + c * 16 + r16] =
                    h1[cc][r] * (acc[cc][r] + bias2[cc]);
            }
        }
    }
}

// ---------------- launch ----------------

extern "C" void kernel_launch(void* const* d_in, const int* in_sizes, int n_in,
                              void* d_out, int out_size, void* d_ws, size_t ws_size,
                              hipStream_t stream) {
    const float* x  = (const float*)d_in[0];
    const int*   ei = (const int*)d_in[1];
    const float* W1 = (const float*)d_in[2];
    const float* b1 = (const float*)d_in[3];
    const float* W2 = (const float*)d_in[4];
    const float* b2 = (const float*)d_in[5];
    float* out = (float*)d_out;

    const int n = NN, e = NE;
    const int* src = ei;          // edge_index[0]
    const int* dst = ei + e;      // edge_index[1]

    char* ws = (char*)d_ws;
    unsigned short* ahi = (unsigned short*)ws;  ws += (size_t)n * D * 2;   // 25.6 MB
    unsigned short* alo = (unsigned short*)ws;  ws += (size_t)n * D * 2;   // 25.6 MB
    short8* wfrag = (short8*)ws;                ws += 8192 * 16;           // 128 KB
    int* counts = (int*)ws;                     ws += (size_t)n * sizeof(int);
    int* offsets = (int*)ws;                    ws += (size_t)(n + 1) * sizeof(int);
    ws += 256 - ((uintptr_t)ws & 255);
    int* cursor = (int*)ws;                     ws += (size_t)n * sizeof(int);
    int* sorted_src = (int*)ws;                 ws += (size_t)e * sizeof(int);
    int* bsum = (int*)ws;                       ws += (size_t)NCH * sizeof(int);
    int* bpre = (int*)ws;                       /* NCH ints */

    zero_kernel<<<(n + 255) / 256, 256, 0, stream>>>(counts, n);
    hist_kernel<<<(e + 255) / 256, 256, 0, stream>>>(dst, counts, e);
    chunk_sum_kernel<<<NCH, 256, 0, stream>>>(counts, bsum, n);
    chunk_scan_kernel<<<1, 128, 0, stream>>>(bsum, bpre, offsets);
    offsets_kernel<<<NCH, CHUNK, 0, stream>>>(counts, bpre, offsets, cursor, n);
    scatter_kernel<<<(e + 255) / 256, 256, 0, stream>>>(src, dst, cursor, sorted_src, e);
    wprep_kernel<<<16, 256, 0, stream>>>(W1, W2, wfrag);
    aggregate_kernel<<<2048, 256, 0, stream>>>(x, offsets, sorted_src, ahi, alo, n);
    fused_kernel<<<256, 512, 0, stream>>>(x, ahi, alo, wfrag, b1, b2, out);
}